// Round 16
// baseline (138.962 us; speedup 1.0000x reference)
//
#include <hip/hip_runtime.h>

// 2-layer tanh RNN, fused, f32, single-wave blocks, no barriers,
// single-buffer LDS state, packed-f32, PERFECT SIMD BALANCE. B=4096,T=512,H=20.
// R16: GB=4 batches/wave, 2 adjacent output rows per lane (10 lanes/batch,
// 40 active lanes) -> 1024 blocks = EXACTLY 1 wave per SIMD chip-wide.
//   R14/R15 model: wall = max(per-SIMD issue, exposed latency).
//   GB=3 (1366 waves) leaves 682 SIMDs with a lone latency-bound wave
//   (~600cyc/iter stragglers). GB=2 balanced but 50% more issue/batch.
//   GB=4 2-row: balanced AND 95cyc issue/batch; latency hidden by ILP
//   (6 independent dot chains per lane x unroll-4 window).
//   waves_per_eu(1,1): RA budget 512 VGPR -> 120 weight scalars resident.

#define Bsz 4096
#define Tn  512
#define Hn  20
#define GB  4                  // batches per wave
#define LPB 10                 // lanes per batch (2 output rows each)
#define XPAD 520               // x row stride: conflict-free
#define NTHREADS 64

typedef float v2 __attribute__((ext_vector_type(2)));

__device__ __forceinline__ float tanh_fast(float v) {
    // tanh(v) = 1 - 2/(exp(2v)+1); v_exp_f32 + v_rcp_f32.
    float e = __expf(2.0f * v);
    return 1.0f - 2.0f * __builtin_amdgcn_rcpf(e + 1.0f);
}

// packed 20-dot: 10 v_pk_fma_f32 over two packed accumulator chains.
#define DOT20P(acc, accb, W, H) do { \
    acc  = __builtin_elementwise_fma(W##0, H##0, acc);  \
    accb = __builtin_elementwise_fma(W##1, H##1, accb); \
    acc  = __builtin_elementwise_fma(W##2, H##2, acc);  \
    accb = __builtin_elementwise_fma(W##3, H##3, accb); \
    acc  = __builtin_elementwise_fma(W##4, H##4, acc);  \
    accb = __builtin_elementwise_fma(W##5, H##5, accb); \
    acc  = __builtin_elementwise_fma(W##6, H##6, acc);  \
    accb = __builtin_elementwise_fma(W##7, H##7, accb); \
    acc  = __builtin_elementwise_fma(W##8, H##8, acc);  \
    accb = __builtin_elementwise_fma(W##9, H##9, accb); \
} while (0)

// load one H=20 row as 10 named v2 SSA values (via float4 vector loads)
#define LOAD_ROWP(W, ptr) \
    v2 W##0, W##1, W##2, W##3, W##4, W##5, W##6, W##7, W##8, W##9; \
    { const float4* _p = (const float4*)(ptr); \
      float4 _t; \
      _t = _p[0]; W##0 = (v2){_t.x, _t.y}; W##1 = (v2){_t.z, _t.w}; \
      _t = _p[1]; W##2 = (v2){_t.x, _t.y}; W##3 = (v2){_t.z, _t.w}; \
      _t = _p[2]; W##4 = (v2){_t.x, _t.y}; W##5 = (v2){_t.z, _t.w}; \
      _t = _p[3]; W##6 = (v2){_t.x, _t.y}; W##7 = (v2){_t.z, _t.w}; \
      _t = _p[4]; W##8 = (v2){_t.x, _t.y}; W##9 = (v2){_t.z, _t.w}; }

// read h-state tile (LDS, broadcast b128) into 10 named v2 values
#define READ_H(H, base) \
    v2 H##0, H##1, H##2, H##3, H##4, H##5, H##6, H##7, H##8, H##9; \
    { const float4 _a = *(const float4*)((base) + 0);  \
      const float4 _b = *(const float4*)((base) + 4);  \
      const float4 _c = *(const float4*)((base) + 8);  \
      const float4 _d = *(const float4*)((base) + 12); \
      const float4 _e = *(const float4*)((base) + 16); \
      H##0 = (v2){_a.x, _a.y}; H##1 = (v2){_a.z, _a.w}; \
      H##2 = (v2){_b.x, _b.y}; H##3 = (v2){_b.z, _b.w}; \
      H##4 = (v2){_c.x, _c.y}; H##5 = (v2){_c.z, _c.w}; \
      H##6 = (v2){_d.x, _d.y}; H##7 = (v2){_d.z, _d.w}; \
      H##8 = (v2){_e.x, _e.y}; H##9 = (v2){_e.z, _e.w}; }

__global__ __launch_bounds__(NTHREADS)
__attribute__((amdgpu_waves_per_eu(1, 1)))
void rnn2_fused(const float* __restrict__ x,        // [B,T,1]
                const float* __restrict__ hidden,   // [2,B,H]
                const float* __restrict__ W_ih0,    // [H,1]
                const float* __restrict__ W_hh0,    // [H,H]
                const float* __restrict__ b_ih0,    // [H]
                const float* __restrict__ b_hh0,    // [H]
                const float* __restrict__ W_ih1,    // [H,H]
                const float* __restrict__ W_hh1,    // [H,H]
                const float* __restrict__ b_ih1,    // [H]
                const float* __restrict__ b_hh1,    // [H]
                const float* __restrict__ fc_w,     // [1,H]
                const float* __restrict__ fc_b,     // [1]
                float* __restrict__ out)            // [B] ++ [2,B,H] flat
{
    const int tid = threadIdx.x;
    const int jj  = tid % LPB;                 // 0..9
    int g = tid / LPB;                         // 0..6
    if (g >= GB) g = GB - 1;                   // lanes 40..63 dup batch 3
                                               // (same-addr same-data: benign)
    const int j0 = 2 * jj;                     // my even output row (j0,j0+1)
    const int b  = blockIdx.x * GB + g;        // 4096 = 1024*4, always valid
    const bool store_ok = (tid < GB * LPB);

    __shared__ float xs[GB][XPAD];     // 8.3 KB
    __shared__ float hs[2][GB][Hn];    // single-buffer state [layer][g][j]

    // ---- per-lane weights: rows j0, j0+1 of the 3 HxH mats (60 v2 values)
    LOAD_ROWP(w0e, W_hh0 + j0 * Hn)
    LOAD_ROWP(w0o, W_hh0 + (j0 + 1) * Hn)
    LOAD_ROWP(w1e, W_ih1 + j0 * Hn)
    LOAD_ROWP(w1o, W_ih1 + (j0 + 1) * Hn)
    LOAD_ROWP(w2e, W_hh1 + j0 * Hn)
    LOAD_ROWP(w2o, W_hh1 + (j0 + 1) * Hn)

    const float wih0e = W_ih0[j0],  wih0o = W_ih0[j0 + 1];
    const float b0e = b_ih0[j0]     + b_hh0[j0];
    const float b0o = b_ih0[j0 + 1] + b_hh0[j0 + 1];
    const float b1e = b_ih1[j0]     + b_hh1[j0];
    const float b1o = b_ih1[j0 + 1] + b_hh1[j0 + 1];

    // ---- stage ALL x (coalesced float4; B divisible by GB -> no clamp)
    {
        const int bB = blockIdx.x * GB;
        #pragma unroll
        for (int r = 0; r < (GB * Tn) / (NTHREADS * 4); ++r) {  // 8 rounds
            const int c  = (r * NTHREADS + tid) * 4;
            const int gg = c >> 9;            // c / 512
            const int t  = c & (Tn - 1);      // c % 512
            float4 v = *(const float4*)(x + (long)(bB + gg) * Tn + t);
            *(float4*)&xs[gg][t] = v;
        }
    }

    // ---- init state: hs[0] = h0[-1], hs[1] = h1[-1]  (j0 even -> float2)
    {
        float2 h0i = *(const float2*)(hidden + b * Hn + j0);
        float2 h1i = *(const float2*)(hidden + (long)Bsz * Hn + b * Hn + j0);
        *(float2*)&hs[0][g][j0] = h0i;
        *(float2*)&hs[1][g][j0] = h1i;
    }
    // single-wave in-order DS pipe: later reads see these writes

    // ---- prologue (i=0): h0[0] = tanh(W_hh0 h0[-1] + x0 wih0 + b0)
    {
        READ_H(hA, &hs[0][g][0])
        const float xt = xs[g][0];
        v2 a0e = (v2){fmaf(xt, wih0e, b0e), 0.f}, a0eb = (v2){0.f, 0.f};
        v2 a0o = (v2){fmaf(xt, wih0o, b0o), 0.f}, a0ob = (v2){0.f, 0.f};
        DOT20P(a0e, a0eb, w0e, hA);
        DOT20P(a0o, a0ob, w0o, hA);
        const v2 se = a0e + a0eb, so = a0o + a0ob;
        *(float2*)&hs[0][g][j0] =
            make_float2(tanh_fast(se.x + se.y), tanh_fast(so.x + so.y));
    }

    // ---- main loop i=1..511: entry: hs[0]=h0[i-1], hs[1]=h1[i-2].
    // computes h0[i], h1[i-1]. 6 independent dot chains/lane -> ILP hides
    // DS latency at 1 wave/SIMD. Unroll-4 window.
    #pragma unroll 4
    for (int i = 1; i < Tn; ++i) {
        READ_H(hA, &hs[0][g][0])
        READ_H(hB, &hs[1][g][0])

        const float xt = xs[g][i];

        v2 a0e = (v2){fmaf(xt, wih0e, b0e), 0.f}, a0eb = (v2){0.f, 0.f};
        v2 a0o = (v2){fmaf(xt, wih0o, b0o), 0.f}, a0ob = (v2){0.f, 0.f};
        v2 a1e = (v2){b1e, 0.f}, a1eb = (v2){0.f, 0.f};
        v2 a1o = (v2){b1o, 0.f}, a1ob = (v2){0.f, 0.f};
        v2 a2e = (v2){0.f, 0.f}, a2eb = (v2){0.f, 0.f};
        v2 a2o = (v2){0.f, 0.f}, a2ob = (v2){0.f, 0.f};

        DOT20P(a0e, a0eb, w0e, hA);
        DOT20P(a0o, a0ob, w0o, hA);
        DOT20P(a1e, a1eb, w1e, hA);
        DOT20P(a1o, a1ob, w1o, hA);
        DOT20P(a2e, a2eb, w2e, hB);
        DOT20P(a2o, a2ob, w2o, hB);

        const v2 s0e = a0e + a0eb, s0o = a0o + a0ob;
        const v2 s1e = (a1e + a1eb) + (a2e + a2eb);
        const v2 s1o = (a1o + a1ob) + (a2o + a2ob);
        *(float2*)&hs[0][g][j0] =
            make_float2(tanh_fast(s0e.x + s0e.y), tanh_fast(s0o.x + s0o.y));
        *(float2*)&hs[1][g][j0] =
            make_float2(tanh_fast(s1e.x + s1e.y), tanh_fast(s1o.x + s1o.y));
    }

    // ---- epilogue (i=512): h1[511] from h0[511], h1[510]
    {
        READ_H(hA, &hs[0][g][0])
        READ_H(hB, &hs[1][g][0])
        v2 a1e = (v2){b1e, 0.f}, a1eb = (v2){0.f, 0.f};
        v2 a1o = (v2){b1o, 0.f}, a1ob = (v2){0.f, 0.f};
        v2 a2e = (v2){0.f, 0.f}, a2eb = (v2){0.f, 0.f};
        v2 a2o = (v2){0.f, 0.f}, a2ob = (v2){0.f, 0.f};
        DOT20P(a1e, a1eb, w1e, hA);
        DOT20P(a1o, a1ob, w1o, hA);
        DOT20P(a2e, a2eb, w2e, hB);
        DOT20P(a2o, a2ob, w2o, hB);
        const v2 s1e = (a1e + a1eb) + (a2e + a2eb);
        const v2 s1o = (a1o + a1ob) + (a2o + a2ob);
        *(float2*)&hs[1][g][j0] =
            make_float2(tanh_fast(s1e.x + s1e.y), tanh_fast(s1o.x + s1o.y));
    }

    // ---- outputs: hs[0]=h0[511], hs[1]=h1[511]
    if (store_ok) {
        *(float2*)(out + Bsz + (long)b * Hn + j0) =
            *(const float2*)&hs[0][g][j0];                        // new_hidden[0]
        *(float2*)(out + Bsz + (long)Bsz * Hn + (long)b * Hn + j0) =
            *(const float2*)&hs[1][g][j0];                        // new_hidden[1]
        if (jj == 0) {                 // fc head: one lane per batch
            LOAD_ROWP(fw, fc_w)
            READ_H(hv, &hs[1][g][0])
            v2 aA = (v2){fc_b[0], 0.f};
            v2 aB = (v2){0.f, 0.f};
            DOT20P(aA, aB, fw, hv);
            const v2 s = aA + aB;
            out[b] = s.x + s.y;
        }
    }
}

extern "C" void kernel_launch(void* const* d_in, const int* in_sizes, int n_in,
                              void* d_out, int out_size, void* d_ws, size_t ws_size,
                              hipStream_t stream) {
    const float* x      = (const float*)d_in[0];
    const float* hidden = (const float*)d_in[1];
    const float* W_ih0  = (const float*)d_in[2];
    const float* W_hh0  = (const float*)d_in[3];
    const float* b_ih0  = (const float*)d_in[4];
    const float* b_hh0  = (const float*)d_in[5];
    const float* W_ih1  = (const float*)d_in[6];
    const float* W_hh1  = (const float*)d_in[7];
    const float* b_ih1  = (const float*)d_in[8];
    const float* b_hh1  = (const float*)d_in[9];
    const float* fc_w   = (const float*)d_in[10];
    const float* fc_b   = (const float*)d_in[11];

    const int nblocks = Bsz / GB;   // 1024 = exactly 1 wave per SIMD
    rnn2_fused<<<nblocks, NTHREADS, 0, stream>>>(
        x, hidden, W_ih0, W_hh0, b_ih0, b_hh0,
        W_ih1, W_hh1, b_ih1, b_hh1, fc_w, fc_b, (float*)d_out);
}